// Round 15
// baseline (334.175 us; speedup 1.0000x reference)
//
#include <hip/hip_runtime.h>
#include <cstdint>
#include <cstddef>

#define HIDDEN 2048
#define HEADS 16
#define HD 128
#define BSZ 2
#define SEQ 2048
#define MTOT (BSZ * SEQ)        // 4096
#define NQKV (HIDDEN + 2 * HD)  // 2304
#define SL2E 0.12751743f        // (1/sqrt(128)) * log2(e)

typedef unsigned short ushort_t;
typedef __attribute__((ext_vector_type(8))) __bf16 bf16x8;
typedef __attribute__((ext_vector_type(4))) float f32x4;
typedef __attribute__((ext_vector_type(16))) float f32x16;

typedef __attribute__((address_space(3))) unsigned int as3_u32;
typedef __attribute__((address_space(1))) const unsigned int as1_u32;

// fp32 -> bf16 round-to-nearest-even
__device__ __forceinline__ ushort_t f2bf(float x) {
  union { float f; unsigned u; } v; v.f = x;
  unsigned r = v.u + 0x7fffu + ((v.u >> 16) & 1u);
  return (ushort_t)(r >> 16);
}
// pack two fp32 -> bf16x2 (truncation; bias cancels in normalized softmax)
__device__ __forceinline__ unsigned pk_bf16(float a, float b) {
  union { float f; unsigned u; } x, y; x.f = a; y.f = b;
  return (x.u >> 16) | (y.u & 0xFFFF0000u);
}

// async global->LDS, 16B per lane; lds dst is wave-uniform (HW adds lane*16)
__device__ __forceinline__ void gld16(const void* g, void* lds) {
  __builtin_amdgcn_global_load_lds((as1_u32*)g, (as3_u32*)lds, 16, 0, 0);
}

// ---------------------------------------------------------------------------
// Fused preprocessing (proven round 9; biasQKV 16 KB — the 4096 B alloc was
// the rounds-6-8 corruption bug). Block ranges (256-thread, block-uniform):
//   [0, NM) mask_flags | [NM,+N0) cvt_bf16 | +N1 cvtT_qkv | +N2 cvtT | +N4 bias
// ---------------------------------------------------------------------------
#define PREP_NM (32 * 16 * BSZ)                  // 1024
#define PREP_N0 (MTOT * HIDDEN / 4 / 256)        // 8192
#define PREP_N1 ((NQKV / 32) * (HIDDEN / 32))    // 4608
#define PREP_N2 ((HIDDEN / 32) * (HIDDEN / 32))  // 4096
#define PREP_N4 ((NQKV + 255) / 256)             // 9
#define PREP_NB (PREP_NM + PREP_N0 + PREP_N1 + PREP_N2 + PREP_N4)

__global__ __launch_bounds__(256) void prep_kernel(
    const float* __restrict__ X, ushort_t* __restrict__ Xb,
    const float* __restrict__ Wq, const float* __restrict__ Wk,
    const float* __restrict__ Wv, ushort_t* __restrict__ WT,
    const float* __restrict__ Wo, ushort_t* __restrict__ WoT,
    const int* __restrict__ mask, int* __restrict__ flags,
    const float* __restrict__ bq, const float* __restrict__ bk,
    const float* __restrict__ bv, float* __restrict__ biasQKV) {
  __shared__ float tileF[32][36];
  __shared__ int sAO[8];
  const int t = threadIdx.x;
  int j = blockIdx.x;

  if (j < PREP_NM) {  // ---- mask_flags (long-pole blocks first) ----
    const int kt = j & 31, qt = (j >> 5) & 15, b = j >> 9;
    int allv = 1, anyv = 0;
    const size_t base = (size_t)b * SEQ * SEQ + (size_t)qt * 128 * SEQ + kt * 64;
    for (int i = t; i < 2048; i += 256) {  // 128 rows x 16 int4
      const int row = i >> 4, c4 = (i & 15) << 2;
      const int4 v = *(const int4*)(mask + base + (size_t)row * SEQ + c4);
      const int nz = (v.x != 0) & (v.y != 0) & (v.z != 0) & (v.w != 0);
      const int nzany = (v.x != 0) | (v.y != 0) | (v.z != 0) | (v.w != 0);
      allv &= nz; anyv |= nzany;
    }
    const int wAll = __all(allv), wAny = __any(anyv);
    if ((t & 63) == 0) { sAO[t >> 6] = wAll; sAO[4 + (t >> 6)] = wAny; }
    __syncthreads();
    if (t == 0) {
      const int A = sAO[0] & sAO[1] & sAO[2] & sAO[3];
      const int O = sAO[4] | sAO[5] | sAO[6] | sAO[7];
      flags[(b * 16 + qt) * 32 + kt] = A ? 2 : (O ? 1 : 0);
    }
    return;
  }
  j -= PREP_NM;

  if (j < PREP_N0) {  // ---- cvt_bf16 (exact coverage, no bounds check) ----
    const int i = j * 256 + t;
    float4 v = ((const float4*)X)[i];
    ushort4 o;
    o.x = f2bf(v.x); o.y = f2bf(v.y); o.z = f2bf(v.z); o.w = f2bf(v.w);
    ((ushort4*)Xb)[i] = o;
    return;
  }
  j -= PREP_N0;

  if (j < PREP_N1) {  // ---- cvtT_qkv ----
    const int nb = (j % (NQKV / 32)) * 32, kb = (j / (NQKV / 32)) * 32;
    const float* W; int N, nc; float scale;
    if (nb < HIDDEN)           { W = Wq; N = HIDDEN; nc = nb;               scale = SL2E; }
    else if (nb < HIDDEN + HD) { W = Wk; N = HD;     nc = nb - HIDDEN;      scale = 1.f; }
    else                       { W = Wv; N = HD;     nc = nb - HIDDEN - HD; scale = 1.f; }
    {
      int row = t >> 3, c4 = (t & 7) << 2;
      float4 v = *(const float4*)(W + (size_t)(kb + row) * N + nc + c4);
      tileF[row][c4] = v.x * scale; tileF[row][c4 + 1] = v.y * scale;
      tileF[row][c4 + 2] = v.z * scale; tileF[row][c4 + 3] = v.w * scale;
    }
    __syncthreads();
    {
      int nl = t >> 3, k4 = (t & 7) << 2;
      ushort4 o;
      o.x = f2bf(tileF[k4 + 0][nl]); o.y = f2bf(tileF[k4 + 1][nl]);
      o.z = f2bf(tileF[k4 + 2][nl]); o.w = f2bf(tileF[k4 + 3][nl]);
      *(ushort4*)(WT + (size_t)(nb + nl) * HIDDEN + kb + k4) = o;
    }
    return;
  }
  j -= PREP_N1;

  if (j < PREP_N2) {  // ---- cvtT (Wo -> WoT), K=N=HIDDEN ----
    const int nb = (j % (HIDDEN / 32)) * 32, kb = (j / (HIDDEN / 32)) * 32;
    {
      int row = t >> 3, c4 = (t & 7) << 2;
      float4 v = *(const float4*)(Wo + (size_t)(kb + row) * HIDDEN + nb + c4);
      tileF[row][c4] = v.x; tileF[row][c4 + 1] = v.y;
      tileF[row][c4 + 2] = v.z; tileF[row][c4 + 3] = v.w;
    }
    __syncthreads();
    {
      int nl = t >> 3, k4 = (t & 7) << 2;
      ushort4 o;
      o.x = f2bf(tileF[k4 + 0][nl]); o.y = f2bf(tileF[k4 + 1][nl]);
      o.z = f2bf(tileF[k4 + 2][nl]); o.w = f2bf(tileF[k4 + 3][nl]);
      *(ushort4*)(WoT + (size_t)(nb + nl) * HIDDEN + kb + k4) = o;
    }
    return;
  }
  j -= PREP_N2;

  {  // ---- concat_bias ----
    const int i = j * 256 + t;
    if (i < NQKV)
      biasQKV[i] = (i < HIDDEN) ? bq[i] * SL2E
                 : (i < HIDDEN + HD ? bk[i - HIDDEN] : bv[i - HIDDEN - HD]);
  }
}

// ---------------------------------------------------------------------------
// bf16 MFMA GEMM, round-21: 128x64 tile + DOUBLE-buffered LDS (48 KB) +
// the proven single-barrier K-loop. Completes the r14 experiment matrix:
// r14 changed tile AND buffering; the -20us came from the 2-full-barrier
// serialization (bounded >=35us), not the tile. This variant keeps r13's
// loop (sync -> prefetch cur^1 -> compute cur) at the smaller tile:
// 48 KB -> 3 blocks/CU (12 waves/CU vs 8), grid 1152/1024 (4+/CU).
// Per wave: 64m x 32n (acc 4x2), 12 b128 reads / 16 MFMA per K-step.
// FUSEV: V n-tiles (nb>=2176) stage transposed into As[0] (exact 16 KB fit,
// r14-validated layout) after an explicit barrier, write Vt coalesced.
// ---------------------------------------------------------------------------
template <int OUTF32, int FUSEV>
__global__ __launch_bounds__(256) void gemm_mfma(
    const ushort_t* __restrict__ A, const ushort_t* __restrict__ Bt,
    const float* __restrict__ bias, void* __restrict__ C,
    ushort_t* __restrict__ Vt, int M, int N, int K, int nm_per_xcd) {
  __shared__ ushort_t As[2][128 * 64];  // 32 KB
  __shared__ ushort_t Bs[2][64 * 64];   // 16 KB
  const int t = threadIdx.x;
  const int w = t >> 6, l = t & 63;
  const int id = blockIdx.x;
  const int xcd = id & 7, j = id >> 3;
  const int mt = xcd * nm_per_xcd + (j % nm_per_xcd);
  const int nt = j / nm_per_xcd;
  const int mb = mt * 128, nb = nt * 64;
  const int wm = (w >> 1) * 64, wn = (w & 1) * 32;
  const int fl = l & 15, g = l >> 4;
  const int srow = l >> 3, cphys = l & 7;

  auto stage = [&](int s, int kt) {
#pragma unroll
    for (int jj = 0; jj < 4; ++jj) {  // A: 128 rows, 16 insts over 4 waves
      const int inst = w * 4 + jj;
      const int row = inst * 8 + srow;
      const int cl = cphys ^ (row & 7);
      gld16(A + (size_t)(mb + row) * K + kt * 64 + cl * 8, &As[s][inst * 512]);
    }
#pragma unroll
    for (int jj = 0; jj < 2; ++jj) {  // B: 64 rows, 8 insts over 4 waves
      const int inst = w * 2 + jj;
      const int row = inst * 8 + srow;
      const int cl = cphys ^ (row & 7);
      gld16(Bt + (size_t)(nb + row) * K + kt * 64 + cl * 8, &Bs[s][inst * 512]);
    }
  };

  f32x4 acc[4][2];
#pragma unroll
  for (int i = 0; i < 4; ++i)
#pragma unroll
    for (int jj = 0; jj < 2; ++jj) acc[i][jj] = (f32x4){0.f, 0.f, 0.f, 0.f};

  stage(0, 0);
  const int nsteps = K >> 6;
  int cur = 0;
  for (int it = 0; it < nsteps; ++it) {
    __syncthreads();  // buf[cur] DMAs drained; prev compute done with cur^1
    if (it + 1 < nsteps) stage(cur ^ 1, it + 1);
    const ushort_t* Ac = &As[cur][0];
    const ushort_t* Bc = &Bs[cur][0];
#pragma unroll
    for (int s = 0; s < 2; ++s) {
      bf16x8 af[4], bfr[2];
#pragma unroll
      for (int i = 0; i < 4; ++i) {
        const int m = wm + i * 16 + fl;
        af[i] = *(const bf16x8*)&Ac[m * 64 + (((s << 2) + g) ^ (m & 7)) * 8];
      }
#pragma unroll
      for (int jj = 0; jj < 2; ++jj) {
        const int n = wn + jj * 16 + fl;
        bfr[jj] = *(const bf16x8*)&Bc[n * 64 + (((s << 2) + g) ^ (n & 7)) * 8];
      }
#pragma unroll
      for (int i = 0; i < 4; ++i)
#pragma unroll
        for (int jj = 0; jj < 2; ++jj)
          acc[i][jj] = __builtin_amdgcn_mfma_f32_16x16x32_bf16(
              af[i], bfr[jj], acc[i][jj], 0, 0, 0);
    }
    cur ^= 1;
  }

  // FUSEV blocks: barrier before overwriting As[0] (dbuf loop has no
  // trailing barrier; branch is block-uniform).
  const bool dofv = FUSEV && (nb >= HIDDEN + HD);
  if (dofv) __syncthreads();

  // epilogue: C stores; dofv blocks also stage V transposed into As[0]
#pragma unroll
  for (int jj = 0; jj < 2; ++jj) {
    const int col = nb + wn + jj * 16 + fl;
    const float bv = bias[col];
#pragma unroll
    for (int i = 0; i < 4; ++i) {
      const int row0 = mb + wm + i * 16 + g * 4;
#pragma unroll
      for (int r = 0; r < 4; ++r) {
        const float val = acc[i][jj][r] + bv;
        if (OUTF32) {
          ((float*)C)[(size_t)(row0 + r) * N + col] = val;
        } else {
          const ushort_t bb = f2bf(val);
          ((ushort_t*)C)[(size_t)(row0 + r) * N + col] = bb;
          if (dofv) {
            // Vs[cl 0..63][rl 0..127], rl XOR-swizzled (r14-validated)
            const int cl = wn + jj * 16 + fl;
            const int rl = row0 - mb + r;
            As[0][cl * 128 + (rl ^ ((cl & 15) << 3))] = bb;
          }
        }
      }
    }
  }

  if (dofv) {
    __syncthreads();
    // coalesced write-out: 64 d-rows x 128 m-cols; 8 ushort4 per thread
    const int vbase = nb - (HIDDEN + HD);  // 0 or 64
    const int rl4 = (t & 31) * 4;
#pragma unroll
    for (int k = 0; k < 8; ++k) {
      const int dl = k * 8 + (t >> 5);
      const ushort4 v =
          *(const ushort4*)&As[0][dl * 128 + (rl4 ^ ((dl & 15) << 3))];
      *(ushort4*)(Vt + (size_t)(vbase + dl) * MTOT + mb + rl4) = v;
    }
  }
}

// ---------------------------------------------------------------------------
// MFMA flash attention (r13: single-buffered V, 48 KB LDS; ~83 us, grid-locked
// at 2 blocks/CU — structural floor for this layout; line closed).
// ---------------------------------------------------------------------------
__global__ __launch_bounds__(256, 2) void flash_mfma(
    const ushort_t* __restrict__ QKV,  // (4096, 2304) bf16; Q pre-scaled
    const ushort_t* __restrict__ Vt,   // (128, 4096) bf16
    const int* __restrict__ mask,      // (B, S, S)
    const int* __restrict__ flags,     // (B, 16, 32)
    ushort_t* __restrict__ Ab)         // (4096, 2048) bf16
{
  __shared__ ushort_t Kbuf[2][64 * 128];  // 32 KB: key rows x 128 k-dim
  __shared__ ushort_t Vbuf[64 * 128];     // 16 KB: single-buffered

  const int qt = blockIdx.x, h = blockIdx.y, b = blockIdx.z;
  const int t = threadIdx.x, w = t >> 6, l = t & 63;
  const int q31 = l & 31, hi = l >> 5;
  const int qbase = qt * 128;
  const int qrow = qbase + w * 32 + q31;  // within-batch q row (B-col index)

  // Q as B-fragments: col=q31, k = ks*16 + hi*8 + j (exp2 domain, pre-scaled)
  bf16x8 qf[8];
#pragma unroll
  for (int ks = 0; ks < 8; ++ks)
    qf[ks] = *(const bf16x8*)(QKV + (size_t)(b * SEQ + qrow) * NQKV + h * HD +
                              ks * 16 + hi * 8);

  // ones B-frag for l: B[col=q31][k] = (q31==0) ? 1.0 : 0
  bf16x8 onesf;
  {
    const ushort_t ov = (q31 == 0) ? (ushort_t)0x3F80 : (ushort_t)0;
#pragma unroll
    for (int jj = 0; jj < 8; ++jj) ((ushort_t*)&onesf)[jj] = ov;
  }

  // prologue: prefetch K(0) -> Kbuf[0] (V staged in-tile; single buffer)
#pragma unroll
  for (int j = 0; j < 4; ++j) {
    const int inst = w * 4 + j;
    const int krow = inst * 4 + (l >> 4);
    const int ck = (l & 15) ^ (krow & 15);
    gld16(QKV + (size_t)(b * SEQ + krow) * NQKV + HIDDEN + ck * 8,
          &Kbuf[0][inst * 512]);
  }

  const size_t mbase = (size_t)b * SEQ * SEQ;

  f32x16 oacc[4], lacc;
#pragma unroll
  for (int d = 0; d < 4; ++d)
#pragma unroll
    for (int r = 0; r < 16; ++r) oacc[d][r] = 0.f;
#pragma unroll
  for (int r = 0; r < 16; ++r) lacc[r] = 0.f;

  int cur = 0;
  for (int kt = 0; kt < SEQ / 64; ++kt) {
    const int kbase = kt * 64;
    const int flag = flags[((b * 16 + qt) << 5) + kt];  // block-uniform
    __syncthreads();  // full drain: K(kt) landed; all waves' PV(kt-1) retired

    // stage V(kt) -> Vbuf (4 loads FIRST; single buffer, freed by barrier)
#pragma unroll
    for (int j = 0; j < 4; ++j) {
      const int inst = w * 4 + j;
      const int vr = inst * 4 + (l >> 4);
      const int clog = (l & 15) ^ (vr & 15);
      const int d = 2 * vr + (clog >> 3);
      gld16(Vt + (size_t)d * MTOT + b * SEQ + kbase + (clog & 7) * 8,
            &Vbuf[inst * 512]);
    }
    // prefetch K(kt+1) -> Kbuf[cur^1] (clamped on last tile)
    {
      const int knb = (kt + 1 < SEQ / 64) ? (kbase + 64) : kbase;
#pragma unroll
      for (int j = 0; j < 4; ++j) {
        const int inst = w * 4 + j;
        const int krow = inst * 4 + (l >> 4);
        const int ck = (l & 15) ^ (krow & 15);
        gld16(QKV + (size_t)(b * SEQ + knb + krow) * NQKV + HIDDEN + ck * 8,
              &Kbuf[cur ^ 1][inst * 512]);
      }
    }

    // ---- S^T = K·Q^T from Kbuf[cur]: A = K rows (key), B = Q cols (q) ----
    const ushort_t* Kc = &Kbuf[cur][0];
    f32x16 sc[2];
#pragma unroll
    for (int kk = 0; kk < 2; ++kk)
#pragma unroll
      for (int r = 0; r < 16; ++r) sc[kk][r] = 0.f;

    __builtin_amdgcn_s_setprio(1);
#pragma unroll
    for (int ks = 0; ks < 8; ++ks)
#pragma unroll
      for (int kk = 0; kk < 2; ++kk) {
        const int key = kk * 32 + q31;  // A-row = lane&31
        const bf16x8 kf = *(const bf16x8*)&Kc[key * 128 +
                                              (((ks << 1) + hi) ^ (key & 15)) * 8];
        sc[kk] = __builtin_amdgcn_mfma_f32_32x32x16_bf16(kf, qf[ks], sc[kk],
                                                         0, 0, 0);
      }
    __builtin_amdgcn_s_setprio(0);

    if (flag != 2) {  // mixed/empty tile: per-element mask fallback
#pragma unroll
      for (int kk = 0; kk < 2; ++kk)
#pragma unroll
        for (int r = 0; r < 16; ++r) {
          const int key = kbase + kk * 32 + (r & 3) + ((r >> 2) << 3) + (hi << 2);
          if (!mask[mbase + (size_t)qrow * SEQ + key]) sc[kk][r] = -1e30f;
        }
    }

    // ---- P = exp2(S^T); pack bf16; permlane32_swap -> PA A-frags in regs ----
    bf16x8 pa[4];
#pragma unroll
    for (int kk = 0; kk < 2; ++kk) {
      float pv[16];
#pragma unroll
      for (int r = 0; r < 16; ++r) pv[r] = __builtin_amdgcn_exp2f(sc[kk][r]);
#pragma unroll
      for (int half = 0; half < 2; ++half) {
        const int bs = half * 8;
        unsigned a0 = pk_bf16(pv[bs + 0], pv[bs + 1]);
        unsigned a1 = pk_bf16(pv[bs + 2], pv[bs + 3]);
        unsigned b0 = pk_bf16(pv[bs + 4], pv[bs + 5]);
        unsigned b1 = pk_bf16(pv[bs + 6], pv[bs + 7]);
        asm("v_permlane32_swap_b32 %0, %1" : "+v"(a0), "+v"(b0));
        asm("v_permlane32_swap_b32 %0, %1" : "+v"(a1), "+v"(b1));
        union { unsigned u[4]; bf16x8 v; } uu;
        uu.u[0] = a0; uu.u[1] = a1; uu.u[2] = b0; uu.u[3] = b1;
        pa[kk * 2 + half] = uu.v;
      }
    }

    // ---- V(kt) ready-wait: own V loads retired (vmcnt(4): K prefetch may
    // stay in flight), then barrier -> ALL waves' V loads landed ----
    asm volatile("s_waitcnt vmcnt(4)" ::: "memory");
    __builtin_amdgcn_s_barrier();
    asm volatile("" ::: "memory");
    __builtin_amdgcn_sched_barrier(0);

    // ---- O += P·V (B-frags from Vbuf, paired-row layout); l += P·ones ----
    __builtin_amdgcn_s_setprio(1);
#pragma unroll
    for (int ks = 0; ks < 4; ++ks) {
#pragma unroll
      for (int dt = 0; dt < 4; ++dt) {
        const int d = dt * 32 + q31;  // B-col = lane&31
        const int vr = d >> 1;
        const int clog = ((d & 1) << 3) + (ks << 1) + hi;
        const bf16x8 vf =
            *(const bf16x8*)&Vbuf[vr * 128 + (clog ^ (vr & 15)) * 8];
        oacc[dt] = __builtin_amdgcn_mfma_f32_32x32x16_bf16(pa[ks], vf,
                                                           oacc[dt], 0, 0, 0);
      }
      lacc = __builtin_amdgcn_mfma_f32_32x32x16_bf16(pa[ks], onesf, lacc,
                                                     0, 0, 0);
    }
    __builtin_amdgcn_s_setprio(0);
    cur ^= 1;
  }

  // ---- epilogue: l lives in col 0 (lanes 0 and 32); D row = q = crow ----
#pragma unroll
  for (int r = 0; r < 16; ++r) {
    const float ls = __shfl(lacc[r], l & 32, 64);
    const float invl = 1.0f / ls;
    const int row = b * SEQ + qbase + w * 32 + (r & 3) + ((r >> 2) << 3) +
                    (hi << 2);
#pragma unroll
    for (int dt = 0; dt < 4; ++dt)
      Ab[(size_t)row * HIDDEN + h * HD + dt * 32 + q31] =
          f2bf(oacc[dt][r] * invl);
  }
}

// ---------------------------------------------------------------------------
extern "C" void kernel_launch(void* const* d_in, const int* in_sizes, int n_in,
                              void* d_out, int out_size, void* d_ws, size_t ws_size,
                              hipStream_t stream) {
  const float* X  = (const float*)d_in[0];
  const int* mask = (const int*)d_in[1];
  const float* Wq = (const float*)d_in[2];
  const float* bq = (const float*)d_in[3];
  const float* Wk = (const float*)d_in[4];
  const float* bk = (const float*)d_in[5];
  const float* Wv = (const float*)d_in[6];
  const float* bv = (const float*)d_in[7];
  const float* Wo = (const float*)d_in[8];
  const float* bo = (const float*)d_in[9];
  float* out = (float*)d_out;

  char* p = (char*)d_ws;
  int* flags     = (int*)p;      p += BSZ * 16 * 32 * 4;   // 4 KB
  float* biasQKV = (float*)p;    p += 16384;  // NQKV floats = 9216 B; 16 KB reserved
  ushort_t* QKVb = (ushort_t*)p; p += (size_t)MTOT * NQKV * 2;
  ushort_t* Xb   = (ushort_t*)p; p += (size_t)MTOT * HIDDEN * 2;  // reused as Ab
  ushort_t* WT   = (ushort_t*)p; p += (size_t)NQKV * HIDDEN * 2;
  ushort_t* WoT  = (ushort_t*)p; p += (size_t)HIDDEN * HIDDEN * 2;
  ushort_t* Vt   = (ushort_t*)p; p += (size_t)HD * MTOT * 2;
  ushort_t* Ab = Xb;  // X consumed by QKV GEMM before flash writes Ab

  // fused preprocessing (mask flags, cvt, weight transposes, bias)
  prep_kernel<<<PREP_NB, 256, 0, stream>>>(
      X, Xb, Wq, Wk, Wv, WT, Wo, WoT, mask, flags, bq, bk, bv, biasQKV);

  // QKV projection: 32 m-tiles x 36 n-tiles(64) -> 1152 blocks (4.5/CU,
  // 48 KB LDS -> 3 co-resident). Epilogue writes Vt (LDS transpose).
  gemm_mfma<0, 1><<<dim3((MTOT / 128) * (NQKV / 64)), 256, 0, stream>>>(
      Xb, WT, biasQKV, QKVb, Vt, MTOT, NQKV, HIDDEN, (MTOT / 128) / 8);
  flash_mfma<<<dim3(SEQ / 128, HEADS, BSZ), 256, 0, stream>>>(
      QKVb, Vt, mask, flags, Ab);
  // O projection: 32 m-tiles x 32 n-tiles(64) -> 1024 blocks
  gemm_mfma<1, 0><<<dim3((MTOT / 128) * (HIDDEN / 64)), 256, 0, stream>>>(
      Ab, WoT, bo, out, nullptr, MTOT, HIDDEN, HIDDEN, (MTOT / 128) / 8);
}

// Round 16
// 313.971 us; speedup vs baseline: 1.0644x; 1.0644x over previous
//
#include <hip/hip_runtime.h>
#include <cstdint>
#include <cstddef>

#define HIDDEN 2048
#define HEADS 16
#define HD 128
#define BSZ 2
#define SEQ 2048
#define MTOT (BSZ * SEQ)        // 4096
#define NQKV (HIDDEN + 2 * HD)  // 2304
#define SL2E 0.12751743f        // (1/sqrt(128)) * log2(e)

typedef unsigned short ushort_t;
typedef __attribute__((ext_vector_type(8))) __bf16 bf16x8;
typedef __attribute__((ext_vector_type(4))) float f32x4;
typedef __attribute__((ext_vector_type(16))) float f32x16;

typedef __attribute__((address_space(3))) unsigned int as3_u32;
typedef __attribute__((address_space(1))) const unsigned int as1_u32;

// fp32 -> bf16 round-to-nearest-even
__device__ __forceinline__ ushort_t f2bf(float x) {
  union { float f; unsigned u; } v; v.f = x;
  unsigned r = v.u + 0x7fffu + ((v.u >> 16) & 1u);
  return (ushort_t)(r >> 16);
}
// pack two fp32 -> bf16x2 (truncation; bias cancels in normalized softmax)
__device__ __forceinline__ unsigned pk_bf16(float a, float b) {
  union { float f; unsigned u; } x, y; x.f = a; y.f = b;
  return (x.u >> 16) | (y.u & 0xFFFF0000u);
}

// async global->LDS, 16B per lane; lds dst is wave-uniform (HW adds lane*16)
__device__ __forceinline__ void gld16(const void* g, void* lds) {
  __builtin_amdgcn_global_load_lds((as1_u32*)g, (as3_u32*)lds, 16, 0, 0);
}

// ---------------------------------------------------------------------------
// Fused preprocessing (proven round 9; biasQKV 16 KB — the 4096 B alloc was
// the rounds-6-8 corruption bug). Block ranges (256-thread, block-uniform):
//   [0, NM) mask_flags | [NM,+N0) cvt_bf16 | +N1 cvtT_qkv | +N2 cvtT | +N4 bias
// ---------------------------------------------------------------------------
#define PREP_NM (32 * 16 * BSZ)                  // 1024
#define PREP_N0 (MTOT * HIDDEN / 4 / 256)        // 8192
#define PREP_N1 ((NQKV / 32) * (HIDDEN / 32))    // 4608
#define PREP_N2 ((HIDDEN / 32) * (HIDDEN / 32))  // 4096
#define PREP_N4 ((NQKV + 255) / 256)             // 9
#define PREP_NB (PREP_NM + PREP_N0 + PREP_N1 + PREP_N2 + PREP_N4)

__global__ __launch_bounds__(256) void prep_kernel(
    const float* __restrict__ X, ushort_t* __restrict__ Xb,
    const float* __restrict__ Wq, const float* __restrict__ Wk,
    const float* __restrict__ Wv, ushort_t* __restrict__ WT,
    const float* __restrict__ Wo, ushort_t* __restrict__ WoT,
    const int* __restrict__ mask, int* __restrict__ flags,
    const float* __restrict__ bq, const float* __restrict__ bk,
    const float* __restrict__ bv, float* __restrict__ biasQKV) {
  __shared__ float tileF[32][36];
  __shared__ int sAO[8];
  const int t = threadIdx.x;
  int j = blockIdx.x;

  if (j < PREP_NM) {  // ---- mask_flags (long-pole blocks first) ----
    const int kt = j & 31, qt = (j >> 5) & 15, b = j >> 9;
    int allv = 1, anyv = 0;
    const size_t base = (size_t)b * SEQ * SEQ + (size_t)qt * 128 * SEQ + kt * 64;
    for (int i = t; i < 2048; i += 256) {  // 128 rows x 16 int4
      const int row = i >> 4, c4 = (i & 15) << 2;
      const int4 v = *(const int4*)(mask + base + (size_t)row * SEQ + c4);
      const int nz = (v.x != 0) & (v.y != 0) & (v.z != 0) & (v.w != 0);
      const int nzany = (v.x != 0) | (v.y != 0) | (v.z != 0) | (v.w != 0);
      allv &= nz; anyv |= nzany;
    }
    const int wAll = __all(allv), wAny = __any(anyv);
    if ((t & 63) == 0) { sAO[t >> 6] = wAll; sAO[4 + (t >> 6)] = wAny; }
    __syncthreads();
    if (t == 0) {
      const int A = sAO[0] & sAO[1] & sAO[2] & sAO[3];
      const int O = sAO[4] | sAO[5] | sAO[6] | sAO[7];
      flags[(b * 16 + qt) * 32 + kt] = A ? 2 : (O ? 1 : 0);
    }
    return;
  }
  j -= PREP_NM;

  if (j < PREP_N0) {  // ---- cvt_bf16 (exact coverage, no bounds check) ----
    const int i = j * 256 + t;
    float4 v = ((const float4*)X)[i];
    ushort4 o;
    o.x = f2bf(v.x); o.y = f2bf(v.y); o.z = f2bf(v.z); o.w = f2bf(v.w);
    ((ushort4*)Xb)[i] = o;
    return;
  }
  j -= PREP_N0;

  if (j < PREP_N1) {  // ---- cvtT_qkv ----
    const int nb = (j % (NQKV / 32)) * 32, kb = (j / (NQKV / 32)) * 32;
    const float* W; int N, nc; float scale;
    if (nb < HIDDEN)           { W = Wq; N = HIDDEN; nc = nb;               scale = SL2E; }
    else if (nb < HIDDEN + HD) { W = Wk; N = HD;     nc = nb - HIDDEN;      scale = 1.f; }
    else                       { W = Wv; N = HD;     nc = nb - HIDDEN - HD; scale = 1.f; }
    {
      int row = t >> 3, c4 = (t & 7) << 2;
      float4 v = *(const float4*)(W + (size_t)(kb + row) * N + nc + c4);
      tileF[row][c4] = v.x * scale; tileF[row][c4 + 1] = v.y * scale;
      tileF[row][c4 + 2] = v.z * scale; tileF[row][c4 + 3] = v.w * scale;
    }
    __syncthreads();
    {
      int nl = t >> 3, k4 = (t & 7) << 2;
      ushort4 o;
      o.x = f2bf(tileF[k4 + 0][nl]); o.y = f2bf(tileF[k4 + 1][nl]);
      o.z = f2bf(tileF[k4 + 2][nl]); o.w = f2bf(tileF[k4 + 3][nl]);
      *(ushort4*)(WT + (size_t)(nb + nl) * HIDDEN + kb + k4) = o;
    }
    return;
  }
  j -= PREP_N1;

  if (j < PREP_N2) {  // ---- cvtT (Wo -> WoT), K=N=HIDDEN ----
    const int nb = (j % (HIDDEN / 32)) * 32, kb = (j / (HIDDEN / 32)) * 32;
    {
      int row = t >> 3, c4 = (t & 7) << 2;
      float4 v = *(const float4*)(Wo + (size_t)(kb + row) * HIDDEN + nb + c4);
      tileF[row][c4] = v.x; tileF[row][c4 + 1] = v.y;
      tileF[row][c4 + 2] = v.z; tileF[row][c4 + 3] = v.w;
    }
    __syncthreads();
    {
      int nl = t >> 3, k4 = (t & 7) << 2;
      ushort4 o;
      o.x = f2bf(tileF[k4 + 0][nl]); o.y = f2bf(tileF[k4 + 1][nl]);
      o.z = f2bf(tileF[k4 + 2][nl]); o.w = f2bf(tileF[k4 + 3][nl]);
      *(ushort4*)(WoT + (size_t)(nb + nl) * HIDDEN + kb + k4) = o;
    }
    return;
  }
  j -= PREP_N2;

  {  // ---- concat_bias ----
    const int i = j * 256 + t;
    if (i < NQKV)
      biasQKV[i] = (i < HIDDEN) ? bq[i] * SL2E
                 : (i < HIDDEN + HD ? bk[i - HIDDEN] : bv[i - HIDDEN - HD]);
  }
}

// ---------------------------------------------------------------------------
// bf16 MFMA GEMM, 2-phase 128x128 double-buffered — the converged optimum
// for this template at these shapes (pair ~160us, 460 TF each; the full
// r10-r15 matrix showed 256^2 8-phase (grid-starved), 128x64 sbuf and
// 128x64 dbuf all 20-85us slower). FUSEV: V tile transposed through reused
// LDS and written coalesced (r12-validated, ~0 cost).
// ---------------------------------------------------------------------------
template <int OUTF32, int FUSEV>
__global__ __launch_bounds__(256) void gemm_mfma(
    const ushort_t* __restrict__ A, const ushort_t* __restrict__ Bt,
    const float* __restrict__ bias, void* __restrict__ C,
    ushort_t* __restrict__ Vt, int M, int N, int K, int nm_per_xcd) {
  __shared__ ushort_t Smem[4 * 128 * 64];  // 64 KB: As[2] | Bs[2]
  ushort_t (*As)[128 * 64] = reinterpret_cast<ushort_t(*)[128 * 64]>(Smem);
  ushort_t (*Bs)[128 * 64] =
      reinterpret_cast<ushort_t(*)[128 * 64]>(Smem + 2 * 128 * 64);
  const int t = threadIdx.x;
  const int w = t >> 6, l = t & 63;
  const int id = blockIdx.x;
  const int xcd = id & 7, j = id >> 3;
  const int mt = xcd * nm_per_xcd + (j % nm_per_xcd);
  const int nt = j / nm_per_xcd;
  const int mb = mt * 128, nb = nt * 128;
  const int wm = (w >> 1) * 64, wn = (w & 1) * 64;
  const int fl = l & 15, g = l >> 4;
  const int srow = l >> 3, cphys = l & 7;

  f32x4 acc[4][4];
#pragma unroll
  for (int i = 0; i < 4; ++i)
#pragma unroll
    for (int jj = 0; jj < 4; ++jj) acc[i][jj] = (f32x4){0.f, 0.f, 0.f, 0.f};

#pragma unroll
  for (int jj = 0; jj < 4; ++jj) {
    const int inst = w * 4 + jj;
    const int row = inst * 8 + srow;
    const int clog = cphys ^ (row & 7);
    gld16(A + (size_t)(mb + row) * K + clog * 8, &As[0][inst * 512]);
    gld16(Bt + (size_t)(nb + row) * K + clog * 8, &Bs[0][inst * 512]);
  }

  int cur = 0;
  for (int k0 = 0; k0 < K; k0 += 64) {
    __syncthreads();
    if (k0 + 64 < K) {
#pragma unroll
      for (int jj = 0; jj < 4; ++jj) {
        const int inst = w * 4 + jj;
        const int row = inst * 8 + srow;
        const int clog = cphys ^ (row & 7);
        gld16(A + (size_t)(mb + row) * K + k0 + 64 + clog * 8,
              &As[cur ^ 1][inst * 512]);
        gld16(Bt + (size_t)(nb + row) * K + k0 + 64 + clog * 8,
              &Bs[cur ^ 1][inst * 512]);
      }
    }
    const ushort_t* Ac = &As[cur][0];
    const ushort_t* Bc = &Bs[cur][0];
#pragma unroll
    for (int s = 0; s < 2; ++s) {
      bf16x8 af[4], bfr[4];
#pragma unroll
      for (int i = 0; i < 4; ++i) {
        const int m = wm + i * 16 + fl;
        af[i] = *(const bf16x8*)&Ac[m * 64 + (((s << 2) + g) ^ (m & 7)) * 8];
        const int n = wn + i * 16 + fl;
        bfr[i] = *(const bf16x8*)&Bc[n * 64 + (((s << 2) + g) ^ (n & 7)) * 8];
      }
#pragma unroll
      for (int i = 0; i < 4; ++i)
#pragma unroll
        for (int jj = 0; jj < 4; ++jj)
          acc[i][jj] = __builtin_amdgcn_mfma_f32_16x16x32_bf16(
              af[i], bfr[jj], acc[i][jj], 0, 0, 0);
    }
    cur ^= 1;
  }

  // V-transpose staging only for the QKV GEMM's V n-tile (nb==2176);
  // branch is block-uniform.
  const bool dofv = FUSEV && (nb == HIDDEN + HD);
  if (dofv) __syncthreads();  // all waves done reading As/Bs; Smem reusable

  // epilogue: C stores (+ LDS-staged V tile for dofv blocks)
#pragma unroll
  for (int jj = 0; jj < 4; ++jj) {
    const int col = nb + wn + jj * 16 + fl;
    const float bv = bias[col];
#pragma unroll
    for (int i = 0; i < 4; ++i) {
      const int row0 = mb + wm + i * 16 + g * 4;
#pragma unroll
      for (int r = 0; r < 4; ++r) {
        const float val = acc[i][jj][r] + bv;
        if (OUTF32) {
          ((float*)C)[(size_t)(row0 + r) * N + col] = val;
        } else {
          const ushort_t bb = f2bf(val);
          ((ushort_t*)C)[(size_t)(row0 + r) * N + col] = bb;
          if (dofv) {
            const int cl = wn + jj * 16 + fl;
            const int rl = row0 - mb + r;
            Smem[cl * 132 + rl] = bb;
          }
        }
      }
    }
  }

  if (dofv) {
    __syncthreads();
    // coalesced write-out: 128 d-rows x 128 cols; each thread 16x ushort4
    const int c4 = (t & 31) * 4;
#pragma unroll
    for (int k = 0; k < 16; ++k) {
      const int d = k * 8 + (t >> 5);
      const ushort4 v = *(const ushort4*)&Smem[d * 132 + c4];
      *(ushort4*)(Vt + (size_t)d * MTOT + mb + c4) = v;
    }
  }
}

// ---------------------------------------------------------------------------
// MFMA flash attention (r13 config, session best: single-buffered V, 48 KB
// LDS, ~83 us; grid-locked 2 blocks/CU — structural floor for this layout).
// ---------------------------------------------------------------------------
__global__ __launch_bounds__(256, 2) void flash_mfma(
    const ushort_t* __restrict__ QKV,  // (4096, 2304) bf16; Q pre-scaled
    const ushort_t* __restrict__ Vt,   // (128, 4096) bf16
    const int* __restrict__ mask,      // (B, S, S)
    const int* __restrict__ flags,     // (B, 16, 32)
    ushort_t* __restrict__ Ab)         // (4096, 2048) bf16
{
  __shared__ ushort_t Kbuf[2][64 * 128];  // 32 KB: key rows x 128 k-dim
  __shared__ ushort_t Vbuf[64 * 128];     // 16 KB: single-buffered

  const int qt = blockIdx.x, h = blockIdx.y, b = blockIdx.z;
  const int t = threadIdx.x, w = t >> 6, l = t & 63;
  const int q31 = l & 31, hi = l >> 5;
  const int qbase = qt * 128;
  const int qrow = qbase + w * 32 + q31;  // within-batch q row (B-col index)

  // Q as B-fragments: col=q31, k = ks*16 + hi*8 + j (exp2 domain, pre-scaled)
  bf16x8 qf[8];
#pragma unroll
  for (int ks = 0; ks < 8; ++ks)
    qf[ks] = *(const bf16x8*)(QKV + (size_t)(b * SEQ + qrow) * NQKV + h * HD +
                              ks * 16 + hi * 8);

  // ones B-frag for l: B[col=q31][k] = (q31==0) ? 1.0 : 0
  bf16x8 onesf;
  {
    const ushort_t ov = (q31 == 0) ? (ushort_t)0x3F80 : (ushort_t)0;
#pragma unroll
    for (int jj = 0; jj < 8; ++jj) ((ushort_t*)&onesf)[jj] = ov;
  }

  // prologue: prefetch K(0) -> Kbuf[0] (V staged in-tile; single buffer)
#pragma unroll
  for (int j = 0; j < 4; ++j) {
    const int inst = w * 4 + j;
    const int krow = inst * 4 + (l >> 4);
    const int ck = (l & 15) ^ (krow & 15);
    gld16(QKV + (size_t)(b * SEQ + krow) * NQKV + HIDDEN + ck * 8,
          &Kbuf[0][inst * 512]);
  }

  const size_t mbase = (size_t)b * SEQ * SEQ;

  f32x16 oacc[4], lacc;
#pragma unroll
  for (int d = 0; d < 4; ++d)
#pragma unroll
    for (int r = 0; r < 16; ++r) oacc[d][r] = 0.f;
#pragma unroll
  for (int r = 0; r < 16; ++r) lacc[r] = 0.f;

  int cur = 0;
  for (int kt = 0; kt < SEQ / 64; ++kt) {
    const int kbase = kt * 64;
    const int flag = flags[((b * 16 + qt) << 5) + kt];  // block-uniform
    __syncthreads();  // full drain: K(kt) landed; all waves' PV(kt-1) retired

    // stage V(kt) -> Vbuf (4 loads FIRST; single buffer, freed by barrier)
#pragma unroll
    for (int j = 0; j < 4; ++j) {
      const int inst = w * 4 + j;
      const int vr = inst * 4 + (l >> 4);
      const int clog = (l & 15) ^ (vr & 15);
      const int d = 2 * vr + (clog >> 3);
      gld16(Vt + (size_t)d * MTOT + b * SEQ + kbase + (clog & 7) * 8,
            &Vbuf[inst * 512]);
    }
    // prefetch K(kt+1) -> Kbuf[cur^1] (clamped on last tile)
    {
      const int knb = (kt + 1 < SEQ / 64) ? (kbase + 64) : kbase;
#pragma unroll
      for (int j = 0; j < 4; ++j) {
        const int inst = w * 4 + j;
        const int krow = inst * 4 + (l >> 4);
        const int ck = (l & 15) ^ (krow & 15);
        gld16(QKV + (size_t)(b * SEQ + knb + krow) * NQKV + HIDDEN + ck * 8,
              &Kbuf[cur ^ 1][inst * 512]);
      }
    }

    // ---- S^T = K·Q^T from Kbuf[cur]: A = K rows (key), B = Q cols (q) ----
    const ushort_t* Kc = &Kbuf[cur][0];
    f32x16 sc[2];
#pragma unroll
    for (int kk = 0; kk < 2; ++kk)
#pragma unroll
      for (int r = 0; r < 16; ++r) sc[kk][r] = 0.f;

    __builtin_amdgcn_s_setprio(1);
#pragma unroll
    for (int ks = 0; ks < 8; ++ks)
#pragma unroll
      for (int kk = 0; kk < 2; ++kk) {
        const int key = kk * 32 + q31;  // A-row = lane&31
        const bf16x8 kf = *(const bf16x8*)&Kc[key * 128 +
                                              (((ks << 1) + hi) ^ (key & 15)) * 8];
        sc[kk] = __builtin_amdgcn_mfma_f32_32x32x16_bf16(kf, qf[ks], sc[kk],
                                                         0, 0, 0);
      }
    __builtin_amdgcn_s_setprio(0);

    if (flag != 2) {  // mixed/empty tile: per-element mask fallback
#pragma unroll
      for (int kk = 0; kk < 2; ++kk)
#pragma unroll
        for (int r = 0; r < 16; ++r) {
          const int key = kbase + kk * 32 + (r & 3) + ((r >> 2) << 3) + (hi << 2);
          if (!mask[mbase + (size_t)qrow * SEQ + key]) sc[kk][r] = -1e30f;
        }
    }

    // ---- P = exp2(S^T); pack bf16; permlane32_swap -> PA A-frags in regs ----
    bf16x8 pa[4];
#pragma unroll
    for (int kk = 0; kk < 2; ++kk) {
      float pv[16];
#pragma unroll
      for (int r = 0; r < 16; ++r) pv[r] = __builtin_amdgcn_exp2f(sc[kk][r]);
#pragma unroll
      for (int half = 0; half < 2; ++half) {
        const int bs = half * 8;
        unsigned a0 = pk_bf16(pv[bs + 0], pv[bs + 1]);
        unsigned a1 = pk_bf16(pv[bs + 2], pv[bs + 3]);
        unsigned b0 = pk_bf16(pv[bs + 4], pv[bs + 5]);
        unsigned b1 = pk_bf16(pv[bs + 6], pv[bs + 7]);
        asm("v_permlane32_swap_b32 %0, %1" : "+v"(a0), "+v"(b0));
        asm("v_permlane32_swap_b32 %0, %1" : "+v"(a1), "+v"(b1));
        union { unsigned u[4]; bf16x8 v; } uu;
        uu.u[0] = a0; uu.u[1] = a1; uu.u[2] = b0; uu.u[3] = b1;
        pa[kk * 2 + half] = uu.v;
      }
    }

    // ---- V(kt) ready-wait: own V loads retired (vmcnt(4): K prefetch may
    // stay in flight), then barrier -> ALL waves' V loads landed ----
    asm volatile("s_waitcnt vmcnt(4)" ::: "memory");
    __builtin_amdgcn_s_barrier();
    asm volatile("" ::: "memory");
    __builtin_amdgcn_sched_barrier(0);

    // ---- O += P·V (B-frags from Vbuf, paired-row layout); l += P·ones ----
    __builtin_amdgcn_s_setprio(1);
#pragma unroll
    for (int ks = 0; ks < 4; ++ks) {
#pragma unroll
      for (int dt = 0; dt < 4; ++dt) {
        const int d = dt * 32 + q31;  // B-col = lane&31
        const int vr = d >> 1;
        const int clog = ((d & 1) << 3) + (ks << 1) + hi;
        const bf16x8 vf =
            *(const bf16x8*)&Vbuf[vr * 128 + (clog ^ (vr & 15)) * 8];
        oacc[dt] = __builtin_amdgcn_mfma_f32_32x32x16_bf16(pa[ks], vf,
                                                           oacc[dt], 0, 0, 0);
      }
      lacc = __builtin_amdgcn_mfma_f32_32x32x16_bf16(pa[ks], onesf, lacc,
                                                     0, 0, 0);
    }
    __builtin_amdgcn_s_setprio(0);
    cur ^= 1;
  }

  // ---- epilogue: l lives in col 0 (lanes 0 and 32); D row = q = crow ----
#pragma unroll
  for (int r = 0; r < 16; ++r) {
    const float ls = __shfl(lacc[r], l & 32, 64);
    const float invl = 1.0f / ls;
    const int row = b * SEQ + qbase + w * 32 + (r & 3) + ((r >> 2) << 3) +
                    (hi << 2);
#pragma unroll
    for (int dt = 0; dt < 4; ++dt)
      Ab[(size_t)row * HIDDEN + h * HD + dt * 32 + q31] =
          f2bf(oacc[dt][r] * invl);
  }
}

// ---------------------------------------------------------------------------
extern "C" void kernel_launch(void* const* d_in, const int* in_sizes, int n_in,
                              void* d_out, int out_size, void* d_ws, size_t ws_size,
                              hipStream_t stream) {
  const float* X  = (const float*)d_in[0];
  const int* mask = (const int*)d_in[1];
  const float* Wq = (const float*)d_in[2];
  const float* bq = (const float*)d_in[3];
  const float* Wk = (const float*)d_in[4];
  const float* bk = (const float*)d_in[5];
  const float* Wv = (const float*)d_in[6];
  const float* bv = (const float*)d_in[7];
  const float* Wo = (const float*)d_in[8];
  const float* bo = (const float*)d_in[9];
  float* out = (float*)d_out;

  char* p = (char*)d_ws;
  int* flags     = (int*)p;      p += BSZ * 16 * 32 * 4;   // 4 KB
  float* biasQKV = (float*)p;    p += 16384;  // NQKV floats = 9216 B; 16 KB reserved
  ushort_t* QKVb = (ushort_t*)p; p += (size_t)MTOT * NQKV * 2;
  ushort_t* Xb   = (ushort_t*)p; p += (size_t)MTOT * HIDDEN * 2;  // reused as Ab
  ushort_t* WT   = (ushort_t*)p; p += (size_t)NQKV * HIDDEN * 2;
  ushort_t* WoT  = (ushort_t*)p; p += (size_t)HIDDEN * HIDDEN * 2;
  ushort_t* Vt   = (ushort_t*)p; p += (size_t)HD * MTOT * 2;
  ushort_t* Ab = Xb;  // X consumed by QKV GEMM before flash writes Ab

  // fused preprocessing (mask flags, cvt, weight transposes, bias)
  prep_kernel<<<PREP_NB, 256, 0, stream>>>(
      X, Xb, Wq, Wk, Wv, WT, Wo, WoT, mask, flags, bq, bk, bv, biasQKV);

  // QKV projection: M=4096 (32 m-tiles), N=2304 (18 n-tiles); nm/8 = 4.
  // Epilogue also writes Vt via LDS-staged coalesced transpose (n-tile 17).
  gemm_mfma<0, 1><<<dim3((MTOT / 128) * (NQKV / 128)), 256, 0, stream>>>(
      Xb, WT, biasQKV, QKVb, Vt, MTOT, NQKV, HIDDEN, (MTOT / 128) / 8);
  flash_mfma<<<dim3(SEQ / 128, HEADS, BSZ), 256, 0, stream>>>(
      QKVb, Vt, mask, flags, Ab);
  // O projection: M=4096 (32 m-tiles), N=2048 (16 n-tiles)
  gemm_mfma<1, 0><<<dim3((MTOT / 128) * (HIDDEN / 128)), 256, 0, stream>>>(
      Ab, WoT, bo, out, nullptr, MTOT, HIDDEN, HIDDEN, (MTOT / 128) / 8);
}